// Round 1
// baseline (216.838 us; speedup 1.0000x reference)
//
#include <hip/hip_runtime.h>

typedef float  f32x4  __attribute__((ext_vector_type(4)));
typedef float  f32x16 __attribute__((ext_vector_type(16)));
typedef short  s16x8  __attribute__((ext_vector_type(8)));
typedef unsigned short u16x4 __attribute__((ext_vector_type(4)));

#define SEQ   2048
#define DH    128
#define BM    128
#define BN    64
#define NT    (SEQ/BN)

// round-half-up fp32 -> bf16 (inputs are finite random normals; no NaN handling needed)
__device__ __forceinline__ unsigned short f2bf(float x){
  unsigned u = __builtin_bit_cast(unsigned, x);
  return (unsigned short)((u + 0x8000u) >> 16);
}

// Flash attention fwd, non-causal.
// Per block: 4 waves, each wave owns 32 q-rows (BM=128). KV tiles of 64.
// QK^T swapped (A=K,B=Q) -> S^T, softmax per-lane (q = lane&31).
// PV as O^T = V^T * P^T (A=V-frag, B=P-frag) -> alpha/normalize lane-uniform.
// K/V staged fp32->bf16 into LDS in fragment-linear layouts (conflict-floor reads).
__global__ __launch_bounds__(256, 2)
void sdpa_fwd(const float* __restrict__ Qg, const float* __restrict__ Kg,
              const float* __restrict__ Vg, float* __restrict__ Og)
{
  __shared__ char kbuf[16384];  // [m(2)][kc(8)][h(2)] x 512B : frag-linear K tile 64x128
  __shared__ char vbuf[16384];  // [ks(4)][dt(4)][h(2)] x 512B : frag-linear V tile 64x128
  __shared__ char pbuf[16384];  // per-wave 4KB: P[32 q][64 kv] bf16, xor-swizzled

  const int tid = threadIdx.x;
  const int w   = tid >> 6;        // wave 0..3
  const int l   = tid & 63;
  const int h2  = l >> 5;          // half-wave 0/1
  const int ln  = l & 31;
  const int c4  = tid & 31;        // staging: float4-column 0..31
  const int rq  = tid >> 5;        // staging: row group 0..7

  const int bid = (int)blockIdx.x;
  // XCD-chunked swizzle: all 16 q-tile blocks of one bh land on one XCD (bid%8),
  // keeping that bh's K/V resident in its 4MB L2.  512 % 8 == 0 -> bijective.
  const int bh  = ((bid & 7) << 2) | ((bid >> 3) & 3);
  const int qt  = bid >> 5;

  const size_t base = (size_t)bh * (SEQ*DH);
  const float* Qb = Qg + base;
  const float* Kb = Kg + base;
  const float* Vb = Vg + base;
  float*       Ob = Og + base;

  const int qrow = qt*BM + w*32 + ln;        // this lane's q row (for Q load + O store)
  const float scale = 0.08838834764831845f;  // 1/sqrt(128), folded into Q before bf16 cvt

  // ---- Q fragments in registers: B-operand, 8 k-steps of 16 ----
  s16x8 qf[8];
#pragma unroll
  for (int kc = 0; kc < 8; ++kc) {
    const float* p = Qb + (size_t)qrow*DH + kc*16 + h2*8;
    f32x4 a = *(const f32x4*)p;
    f32x4 b = *(const f32x4*)(p+4);
    s16x8 r;
    r[0] = (short)f2bf(a[0]*scale); r[1] = (short)f2bf(a[1]*scale);
    r[2] = (short)f2bf(a[2]*scale); r[3] = (short)f2bf(a[3]*scale);
    r[4] = (short)f2bf(b[0]*scale); r[5] = (short)f2bf(b[1]*scale);
    r[6] = (short)f2bf(b[2]*scale); r[7] = (short)f2bf(b[3]*scale);
    qf[kc] = r;
  }

  // O^T accumulator: lane holds O[q=ln][d = 32*dt + (reg&3)+8*(reg>>2)+4*h2]
  f32x16 ot[4];
#pragma unroll
  for (int dt = 0; dt < 4; ++dt)
#pragma unroll
    for (int r = 0; r < 16; ++r) ot[dt][r] = 0.f;

  float m_run = -1e30f, l_run = 0.f;

  // staging registers (fp32, converted at LDS-write time)
  f32x4 kst[8], vst[8];

  auto fetch = [&](int t) {
    const int kv0 = t * BN;
#pragma unroll
    for (int kk = 0; kk < 8; ++kk)
      kst[kk] = *(const f32x4*)(Kb + (size_t)(kv0 + rq + kk*8)*DH + c4*4);
#pragma unroll
    for (int it = 0; it < 2; ++it)
#pragma unroll
      for (int i = 0; i < 4; ++i)
        vst[it*4+i] = *(const f32x4*)(Vb + (size_t)(kv0 + (rq + it*8)*4 + i)*DH + c4*4);
  };

  fetch(0);

  for (int t = 0; t < NT; ++t) {
    __syncthreads();              // previous tile's compute done; LDS writable

    // ---- stage K: element (kv, c): frag (m=kv>>5, kc=c>>4, h=(c>>3)&1), slot=kv&31, j=c&7
    //      byte = frag*512 + ((slot ^ Wk)<<4) + (j&4)*2,  Wk=(2*kc+h)&7
#pragma unroll
    for (int kk = 0; kk < 8; ++kk) {
      const int kv  = rq + kk*8;
      const int mm  = kv >> 5, r31 = kv & 31;
      const int kc  = c4 >> 2, hh = (c4 >> 1) & 1;
      const int Wk  = (2*kc + hh) & 7;
      const int byt = (((mm*8 + kc)*2 + hh) << 9) | ((r31 ^ Wk) << 4) | ((c4 & 1) << 3);
      u16x4 v;
      v[0] = f2bf(kst[kk][0]); v[1] = f2bf(kst[kk][1]);
      v[2] = f2bf(kst[kk][2]); v[3] = f2bf(kst[kk][3]);
      *(u16x4*)(kbuf + byt) = v;
    }
    // ---- stage V (register 4x4 transpose): element (kv, d):
    //      frag (ks=kv>>4, dt=d>>5, h=(kv>>3)&1), slot=d&31, j=kv&7
#pragma unroll
    for (int it = 0; it < 2; ++it) {
      const int rqp = rq + it*8;
      const int ks  = rqp >> 2, hp = (rqp >> 1) & 1, j0b = (rqp & 1) << 3;
#pragma unroll
      for (int ii = 0; ii < 4; ++ii) {
        const int dt  = c4 >> 3;
        const int d31 = ((c4 & 7) << 2) | ii;
        const int Wv  = (2*dt + hp) & 7;
        const int byt = (((ks*4 + dt)*2 + hp) << 9) | ((d31 ^ Wv) << 4) | j0b;
        u16x4 v;
        v[0] = f2bf(vst[it*4+0][ii]); v[1] = f2bf(vst[it*4+1][ii]);
        v[2] = f2bf(vst[it*4+2][ii]); v[3] = f2bf(vst[it*4+3][ii]);
        *(u16x4*)(vbuf + byt) = v;
      }
    }
    if (t + 1 < NT) fetch(t + 1);   // issue next tile's global loads; drain at next write
    __syncthreads();                // K/V tile visible

    // ---- QK^T: S^T[kv][q], two 32-row kv tiles ----
    f32x16 sa[2];
#pragma unroll
    for (int mm = 0; mm < 2; ++mm) {
#pragma unroll
      for (int r = 0; r < 16; ++r) sa[mm][r] = 0.f;
#pragma unroll
      for (int kc = 0; kc < 8; ++kc) {
        const int byt = (((mm*8 + kc)*2 + h2) << 9) | ((ln ^ ((2*kc + h2) & 7)) << 4);
        s16x8 a = *(const s16x8*)(kbuf + byt);   // A: K[32mm+ln][16kc+8h2+j]
        sa[mm] = __builtin_amdgcn_mfma_f32_32x32x16_bf16(a, qf[kc], sa[mm], 0, 0, 0);
      }
    }

    // ---- online softmax (q = ln; kv per lane = 32mm + (r&3)+8*(r>>2)+4*h2) ----
    float tmax = sa[0][0];
#pragma unroll
    for (int mm = 0; mm < 2; ++mm)
#pragma unroll
      for (int r = 0; r < 16; ++r) tmax = fmaxf(tmax, sa[mm][r]);
    tmax = fmaxf(tmax, __shfl_xor(tmax, 32));
    const float mnew  = fmaxf(m_run, tmax);
    const float alpha = __expf(m_run - mnew);   // first tile: exp(-1e30) -> 0
    float psum = 0.f;
    const int wbase = w << 12;
#pragma unroll
    for (int mm = 0; mm < 2; ++mm)
#pragma unroll
      for (int tq = 0; tq < 4; ++tq) {
        u16x4 pk;
#pragma unroll
        for (int rr = 0; rr < 4; ++rr) {
          const float pv = __expf(sa[mm][tq*4+rr] - mnew);
          psum += pv;
          pk[rr] = f2bf(pv);
        }
        // P[q=ln][kv = 32mm+8tq+4h2 .. +3]; byte = q*128 + (kv*2 ^ ((q&7)<<4))
        const int byt = wbase | (ln << 7) | ((mm*64 + tq*16 + h2*8) ^ ((ln & 7) << 4));
        *(u16x4*)(pbuf + byt) = pk;
      }
    psum += __shfl_xor(psum, 32);
    l_run = l_run * alpha + psum;
    m_run = mnew;
#pragma unroll
    for (int dt = 0; dt < 4; ++dt)
#pragma unroll
      for (int r = 0; r < 16; ++r) ot[dt][r] *= alpha;

    asm volatile("s_waitcnt lgkmcnt(0)" ::: "memory");  // P writes visible to own wave's reads
    __builtin_amdgcn_sched_barrier(0);

    // ---- PV: O^T += V^T-frag x P^T-frag ----
#pragma unroll
    for (int ks = 0; ks < 4; ++ks) {
      const int pbyt = wbase | (ln << 7) | ((ks*32 + h2*16) ^ ((ln & 7) << 4));
      s16x8 pb = *(const s16x8*)(pbuf + pbyt);  // B: P[q=ln][16ks+8h2+j]
#pragma unroll
      for (int dt = 0; dt < 4; ++dt) {
        const int vbyt = (((ks*4 + dt)*2 + h2) << 9) | ((ln ^ ((2*dt + h2) & 7)) << 4);
        s16x8 va = *(const s16x8*)(vbuf + vbyt); // A: V[16ks+8h2+j][32dt+ln]
        ot[dt] = __builtin_amdgcn_mfma_f32_32x32x16_bf16(va, pb, ot[dt], 0, 0, 0);
      }
    }
  }

  // ---- epilogue: normalize + store (lane-uniform 1/l, float4 stores) ----
  const float inv = 1.0f / l_run;
#pragma unroll
  for (int dt = 0; dt < 4; ++dt)
#pragma unroll
    for (int tq = 0; tq < 4; ++tq) {
      f32x4 o;
      o[0] = ot[dt][tq*4+0]*inv; o[1] = ot[dt][tq*4+1]*inv;
      o[2] = ot[dt][tq*4+2]*inv; o[3] = ot[dt][tq*4+3]*inv;
      const int d0 = dt*32 + tq*8 + h2*4;
      *(f32x4*)(Ob + (size_t)qrow*DH + d0) = o;
    }
}

extern "C" void kernel_launch(void* const* d_in, const int* in_sizes, int n_in,
                              void* d_out, int out_size, void* d_ws, size_t ws_size,
                              hipStream_t stream)
{
  (void)in_sizes; (void)n_in; (void)d_ws; (void)ws_size; (void)out_size;
  const float* Q = (const float*)d_in[0];
  const float* K = (const float*)d_in[1];
  const float* V = (const float*)d_in[2];
  float* O = (float*)d_out;
  dim3 grid(512), block(256);
  hipLaunchKernelGGL(sdpa_fwd, grid, block, 0, stream, Q, K, V, O);
}